// Round 3
// baseline (106.812 us; speedup 1.0000x reference)
//
#include <hip/hip_runtime.h>
#include <math.h>

#define TOPK 2048
#define NCLS 80      // reference: randint(0, 80)
#define NBIN 4096    // score-digest bins (uniform scores -> ~5/bin)
#define CMAX 2560    // candidate key capacity (K + tie-bin slack)
#define K1B  32      // selection blocks (candidate partition by idx & 31)
#define STN  1024    // k_sel threads (16 waves)
#define CTN  256     // k_cmp threads
#define CROWS 2      // k_cmp rows per block -> 1024 blocks

struct SelP {
    const float* scores; const float* boxes; const int* classes;
    int M; int K;
    float4* sel_box; float* sel_score; int* sel_cls;
    int* cstart;      // [NCLS+1] exclusive class starts (written by block 0)
    short* clist;     // [K] row indices grouped by class (written by block 0)
};

struct CmpP {
    const float4* sel_box; const float* sel_score; const int* sel_cls;
    const int* cstart; const short* clist;
    const float* sw1; const float* sb1; const float* sw2; const float* sb2;
    const float* sw3; const float* sb3;
    const float* lw1; const float* lb1; const float* lw2; const float* lb2;
    int K;
    float* out_boxes; float* out_scores; float* out_cls;
};

__device__ __forceinline__ float iou_of(float xi, float yi, float ai,
                                        float x2i, float y2i, float4 bj) {
    float ix1 = fmaxf(xi, bj.x), iy1 = fmaxf(yi, bj.y);
    float ix2 = fminf(x2i, bj.x + bj.z), iy2 = fminf(y2i, bj.y + bj.w);
    float iw = fmaxf(ix2 - ix1, 0.0f), ih = fmaxf(iy2 - iy1, 0.0f);
    float inter = iw * ih;
    float uni = ai + bj.z * bj.w - inter;
    return inter / (uni + 1e-6f);
}

// monotone non-decreasing digest; single quantization used in all passes
__device__ __forceinline__ int digest12(float s) {
    int v = (int)(s * 4096.0f);
    return v < 0 ? 0 : (v > NBIN - 1 ? NBIN - 1 : v);
}

__device__ __forceinline__ float key_score(unsigned long long kk) {
    unsigned mono = (unsigned)(kk >> 32);
    unsigned ob = (mono & 0x80000000u) ? (mono & 0x7FFFFFFFu) : ~mono;
    return __uint_as_float(ob);
}

// ---------------------------------------------------------------------------
// k_sel: 32 blocks redundantly find the exact top-K (jax.lax.top_k stable
// semantics) via binned counting-rank. Round-3 changes:
//  - NO ssc LDS score cache: the 80 KB score array is L2-resident after
//    sweep 1 (Common-mistake #7); sweep 2 re-reads it as float4 from L2.
//    LDS 140 KB -> ~78 KB, fewer LDS ops on the critical path.
//  - k_prep is FOLDED into block 0: every block holds ALL candidate keys
//    (redundant-sweep design), so block 0 ranks every candidate and builds
//    cstart/clist alone (single writer -> no cross-block ordering hazard).
//    One fewer kernel launch + serialization gap.
// ---------------------------------------------------------------------------
__global__ __launch_bounds__(STN, 1) void k_sel(SelP p) {
    __shared__ int   bincur[NBIN];                // 16 KB count -> cursor
    __shared__ int   binbase[NBIN];               // 16 KB rank base
    __shared__ unsigned long long skeys[CMAX];    // 20 KB candidate keys
    __shared__ int   sfx[STN];                    // 4 KB inclusive suffix sums
    __shared__ int   wsum[STN / 64];              // wave-total suffix sums
    __shared__ int   sh_cT;
    // prep state (used by block 0 only; freed by dropping ssc)
    __shared__ int   cls_of[CMAX];                // 10 KB class per candidate
    __shared__ int   rk_of[CMAX];                 // 10 KB rank per candidate
    __shared__ int   ccnt[NCLS], ccur[NCLS];
    __shared__ int   wtot;

    int tid = threadIdx.x, bid = blockIdx.x;
    int M = p.M, K = p.K, M4 = M >> 2;
    bool prep = (bid == 0);

    for (int b = tid; b < NBIN; b += STN) bincur[b] = 0;
    if (tid < NCLS) ccnt[tid] = 0;
    __syncthreads();

    // ---- sweep 1: histogram straight from global (vectorized) ----
    const float4* s4p = (const float4*)p.scores;
    for (int i4 = tid; i4 < M4; i4 += STN) {
        float4 v = s4p[i4];
        atomicAdd(&bincur[digest12(v.x)], 1);
        atomicAdd(&bincur[digest12(v.y)], 1);
        atomicAdd(&bincur[digest12(v.z)], 1);
        atomicAdd(&bincur[digest12(v.w)], 1);
    }
    for (int i = M4 * 4 + tid; i < M; i += STN)
        atomicAdd(&bincur[digest12(p.scores[i])], 1);
    __syncthreads();

    // ---- suffix scan (shuffle-based): sfx[t] = sum of chunk sums t.. ----
    {
        const int BPT = NBIN / STN;               // 4 bins per thread
        int c0 = tid * BPT, sum = 0;
        #pragma unroll
        for (int u = 0; u < BPT; u++) sum += bincur[c0 + u];
        int lane = tid & 63;
        int x = sum;
        #pragma unroll
        for (int off = 1; off < 64; off <<= 1) {  // in-wave inclusive suffix
            int v = __shfl_down(x, off, 64);
            if (lane + off < 64) x += v;
        }
        if (lane == 0) wsum[tid >> 6] = x;        // wave totals (16)
        __syncthreads();
        if (tid < STN / 64) {                     // suffix over wave totals
            int t = wsum[tid];
            #pragma unroll
            for (int off = 1; off < STN / 64; off <<= 1) {
                int v = __shfl_down(t, off, 64);
                if (tid + off < STN / 64) t += v;
            }
            wsum[tid] = t;
        }
        __syncthreads();
        int wid = tid >> 6;
        int higher = (wid < STN / 64 - 1) ? wsum[wid + 1] : 0;
        sfx[tid] = x + higher;                    // global inclusive suffix
    }
    __syncthreads();

    // ---- binbase per bin + find crossing bin cT ----
    {
        const int BPT = NBIN / STN;
        int running = (tid < STN - 1) ? sfx[tid + 1] : 0;
        int c0 = tid * BPT;
        for (int u = BPT - 1; u >= 0; u--) {
            int b = c0 + u, cnt = bincur[b];
            binbase[b] = running;
            if (running < K && running + cnt >= K) sh_cT = b;  // unique bin
            running += cnt;
        }
    }
    __syncthreads();
    int cT = sh_cT;
    for (int b = tid; b < NBIN; b += STN) bincur[b] = binbase[b];
    __syncthreads();

    // ---- sweep 2 (from L2, vectorized): scatter candidate keys ----
    // key = monotonic(score bits) << 32 | (0xFFFFFFFF - i): descending key ==
    // descending score, ties -> lower index (stable top_k semantics).
    for (int i4 = tid; i4 < M4; i4 += STN) {
        float4 v = s4p[i4];
        #pragma unroll
        for (int u = 0; u < 4; u++) {
            float s = (u == 0) ? v.x : (u == 1) ? v.y : (u == 2) ? v.z : v.w;
            int d = digest12(s);
            if (d >= cT) {
                int i = i4 * 4 + u;
                int slot = atomicAdd(&bincur[d], 1);
                if (slot < CMAX) {
                    unsigned b = __float_as_uint(s);
                    b = (b & 0x80000000u) ? ~b : (b | 0x80000000u);
                    skeys[slot] = ((unsigned long long)b << 32) |
                                  (unsigned long long)(0xFFFFFFFFu - (unsigned)i);
                }
            }
        }
    }
    for (int i = M4 * 4 + tid; i < M; i += STN) {
        float s = p.scores[i];
        int d = digest12(s);
        if (d >= cT) {
            int slot = atomicAdd(&bincur[d], 1);
            if (slot < CMAX) {
                unsigned b = __float_as_uint(s);
                b = (b & 0x80000000u) ? ~b : (b | 0x80000000u);
                skeys[slot] = ((unsigned long long)b << 32) |
                              (unsigned long long)(0xFFFFFFFFu - (unsigned)i);
            }
        }
    }
    __syncthreads();

    // ---- exact rank within bin (~5 peers) + gather/write own partition;
    //      block 0 additionally records (rank, class) for every candidate ----
    int C = bincur[cT]; if (C > CMAX) C = CMAX;
    {
        const float4* boxes4 = (const float4*)p.boxes;
        for (int s = tid; s < C; s += STN) {
            unsigned long long ks = skeys[s];
            unsigned idx = 0xFFFFFFFFu - (unsigned)(ks & 0xFFFFFFFFull);
            bool mine = ((int)(idx & (K1B - 1)) == bid);
            if (!prep && !mine) continue;
            float sc = key_score(ks);
            int d = digest12(sc);
            int st = binbase[d], en = bincur[d]; if (en > CMAX) en = CMAX;
            int r = binbase[d];
            for (int t = st; t < en; t++) r += (skeys[t] > ks) ? 1 : 0;
            bool ok = (r < K);
            int c = -1;
            if (ok) c = p.classes[idx];
            if (prep) {
                cls_of[s] = ok ? c : -1;
                rk_of[s] = r;
                if (ok) atomicAdd(&ccnt[c], 1);
            }
            if (mine && ok) {
                p.sel_box[r] = boxes4[idx];
                p.sel_score[r] = sc;
                p.sel_cls[r] = c;
            }
        }
    }
    __syncthreads();

    // ---- block 0: class-list build (old k_prep, same verified scan) ----
    if (prep) {
        int x = 0, v = 0;
        if (tid < 128) {
            v = (tid < NCLS) ? ccnt[tid] : 0;
            x = v;
            #pragma unroll
            for (int off = 1; off < 64; off <<= 1) {
                int t = __shfl_up(x, off, 64);
                if ((tid & 63) >= off) x += t;
            }
            if (tid == 63) wtot = x;              // total of classes 0..63
        }
        __syncthreads();
        if (tid < NCLS) {
            int excl = x - v + ((tid >= 64) ? wtot : 0);
            ccur[tid] = excl;
            p.cstart[tid] = excl;
        }
        if (tid == 0) p.cstart[NCLS] = K;
        __syncthreads();
        for (int s = tid; s < C; s += STN) {
            int c = cls_of[s];
            if (c >= 0) {
                int pos = atomicAdd(&ccur[c], 1);
                p.clist[pos] = (short)rk_of[s];
            }
        }
    }
}

// ---------------------------------------------------------------------------
// k_cmp: 1024 blocks x 2 rows.  [UNCHANGED from round 2 -- no spill,
// weights in 3.7 KB LDS, sel arrays read straight from L2.]
// ---------------------------------------------------------------------------
__global__ __launch_bounds__(CTN, 2) void k_cmp(CmpP p) {
    __shared__ float swt[914];                    // sup MLP 801 + lambda 113
    __shared__ float wpart[8];                    // [wave][row] D partials
    __shared__ int   rowc[CROWS];                 // class start per row
    __shared__ int   prefix[CROWS + 1];
    __shared__ float Ssum[CROWS], Drow[CROWS];

    int tid = threadIdx.x, bid = blockIdx.x;
    int K = p.K;
    int r0 = bid * CROWS;
    int nrows = K - r0; if (nrows > CROWS) nrows = CROWS;
    if (nrows <= 0) return;

    // ---- stage MLP weights (only LDS staging) ----
    for (int t = tid; t < 224; t += CTN) swt[t] = p.sw1[t];
    if (tid < 32) swt[224 + tid] = p.sb1[tid];
    for (int t = tid; t < 512; t += CTN) swt[256 + t] = p.sw2[t];
    if (tid < 16) swt[768 + tid] = p.sb2[tid];
    if (tid < 16) swt[784 + tid] = p.sw3[tid];
    if (tid == 0) swt[800] = p.sb3[0];
    if (tid < 80) swt[801 + tid] = p.lw1[tid];
    if (tid < 16) swt[881 + tid] = p.lb1[tid];
    if (tid < 16) swt[897 + tid] = p.lw2[tid];
    if (tid == 0) swt[913] = p.lb2[0];

    // ---- per-row class range from precomputed cstart ----
    if (tid < CROWS) {
        Ssum[tid] = 0.0f;
        int st = 0, cnt = 0;
        if (tid < nrows) {
            int c = p.sel_cls[r0 + tid];
            st = p.cstart[c];
            cnt = p.cstart[c + 1] - st;
        }
        rowc[tid] = st;
        prefix[tid] = cnt;                        // temp: counts
    }
    __syncthreads();
    if (tid == 0) {                               // 2-element prefix
        int a0 = prefix[0], a1 = prefix[1];
        prefix[0] = 0; prefix[1] = a0; prefix[2] = a0 + a1;
    }

    // ---- Phase A: D row means; each thread loads bj once, feeds BOTH rows ----
    {
        float4 bi0 = p.sel_box[r0];
        float4 bi1 = (nrows > 1) ? p.sel_box[r0 + 1] : bi0;
        float a0 = bi0.z * bi0.w, x20 = bi0.x + bi0.z, y20 = bi0.y + bi0.w;
        float a1 = bi1.z * bi1.w, x21 = bi1.x + bi1.z, y21 = bi1.y + bi1.w;
        float d0 = 0.0f, d1 = 0.0f;
        for (int j = tid; j < K; j += CTN) {
            float4 bj = p.sel_box[j];
            d0 += iou_of(bi0.x, bi0.y, a0, x20, y20, bj);
            d1 += iou_of(bi1.x, bi1.y, a1, x21, y21, bj);
        }
        #pragma unroll
        for (int off = 32; off >= 1; off >>= 1) {
            d0 += __shfl_xor(d0, off, 64);
            d1 += __shfl_xor(d1, off, 64);
        }
        int lane = tid & 63, wv = tid >> 6;
        if (lane == 0) { wpart[wv * 2] = d0; wpart[wv * 2 + 1] = d1; }
    }
    __syncthreads();
    if (tid < nrows)
        Drow[tid] = (wpart[tid] + wpart[2 + tid] + wpart[4 + tid] + wpart[6 + tid])
                    / (float)K;

    int Pb = prefix[CROWS];
    const float* W1 = swt;       const float* B1 = swt + 224;
    const float* W2 = swt + 256; const float* B2 = swt + 768;
    const float* W3 = swt + 784; float B3 = swt[800];

    // ---- Phase B: flat per-pair fused MLP (j from precomputed clist) ----
    for (int pp = tid; pp < Pb; pp += CTN) {
        int row = (pp >= prefix[1]) ? 1 : 0;
        int j = (int)p.clist[rowc[row] + (pp - prefix[row])];
        float4 bi = p.sel_box[r0 + row];
        float4 bj = p.sel_box[j];
        float ai = bi.z * bi.w, x2i = bi.x + bi.z, y2i = bi.y + bi.w;
        float iou = iou_of(bi.x, bi.y, ai, x2i, y2i, bj);
        float f1 = fabsf(bi.x - bj.x), f2 = fabsf(bi.y - bj.y);
        float f3 = fabsf(bi.z - bj.z), f4 = fabsf(bi.w - bj.w);
        float f5 = p.sel_score[r0 + row], f6 = p.sel_score[j];
        float acc2[16];
        #pragma unroll
        for (int q = 0; q < 16; q++) acc2[q] = B2[q];
        #pragma unroll 2
        for (int o = 0; o < 32; o++) {
            float a = B1[o];
            a += iou * W1[0 * 32 + o];
            a += f1 * W1[1 * 32 + o];
            a += f2 * W1[2 * 32 + o];
            a += f3 * W1[3 * 32 + o];
            a += f4 * W1[4 * 32 + o];
            a += f5 * W1[5 * 32 + o];
            a += f6 * W1[6 * 32 + o];
            float h = fmaxf(a, 0.0f);
            #pragma unroll
            for (int q = 0; q < 16; q++) acc2[q] += h * W2[o * 16 + q];
        }
        float acc3 = B3;
        #pragma unroll
        for (int q = 0; q < 16; q++) acc3 += fmaxf(acc2[q], 0.0f) * W3[q];
        atomicAdd(&Ssum[row], iou / (1.0f + expf(-acc3)));
    }
    __syncthreads();

    // ---- finale: lambda MLP + outputs for this block's rows ----
    if (tid < nrows) {
        int r = r0 + tid;
        float4 bi = p.sel_box[r];
        float si = p.sel_score[r];
        const float* LW1 = swt + 801; const float* LB1 = swt + 881;
        const float* LW2 = swt + 897; float LB2 = swt[913];
        float in5[5] = { bi.x, bi.y, bi.z, bi.w, si };
        float acc = LB2;
        #pragma unroll
        for (int o = 0; o < 16; o++) {
            float a2 = LB1[o];
            #pragma unroll
            for (int f = 0; f < 5; f++) a2 += in5[f] * LW1[f * 16 + o];
            acc += fmaxf(a2, 0.0f) * LW2[o];
        }
        float lam = 1.0f / (1.0f + expf(-acc));
        ((float4*)p.out_boxes)[r] = bi;
        p.out_cls[r] = (float)p.sel_cls[r];
        p.out_scores[r] = si * expf(-lam * Ssum[tid] * Drow[tid]);
    }
}

extern "C" void kernel_launch(void* const* d_in, const int* in_sizes, int n_in,
                              void* d_out, int out_size, void* d_ws, size_t ws_size,
                              hipStream_t stream) {
    int M = in_sizes[1];
    int K = (M < TOPK) ? M : TOPK;

    char* ws = (char*)d_ws;
    float4* sel_box   = (float4*)ws;           ws += (size_t)TOPK * 16;
    float*  sel_score = (float*)ws;            ws += (size_t)TOPK * 4;
    int*    sel_cls   = (int*)ws;              ws += (size_t)TOPK * 4;
    int*    cstart    = (int*)ws;              ws += (size_t)(NCLS + 2) * 4;
    short*  clist     = (short*)ws;            ws += (size_t)TOPK * 2;

    SelP sp;
    sp.scores  = (const float*)d_in[1];
    sp.boxes   = (const float*)d_in[0];
    sp.classes = (const int*)d_in[2];
    sp.M = M; sp.K = K;
    sp.sel_box = sel_box; sp.sel_score = sel_score; sp.sel_cls = sel_cls;
    sp.cstart = cstart; sp.clist = clist;

    CmpP cp;
    cp.sel_box = sel_box; cp.sel_score = sel_score; cp.sel_cls = sel_cls;
    cp.cstart = cstart; cp.clist = clist;
    cp.sw1 = (const float*)d_in[3];  cp.sb1 = (const float*)d_in[4];
    cp.sw2 = (const float*)d_in[5];  cp.sb2 = (const float*)d_in[6];
    cp.sw3 = (const float*)d_in[7];  cp.sb3 = (const float*)d_in[8];
    cp.lw1 = (const float*)d_in[9];  cp.lb1 = (const float*)d_in[10];
    cp.lw2 = (const float*)d_in[11]; cp.lb2 = (const float*)d_in[12];
    cp.K = K;
    cp.out_boxes  = (float*)d_out;
    cp.out_scores = (float*)d_out + (size_t)K * 4;
    cp.out_cls    = (float*)d_out + (size_t)K * 5;

    k_sel<<<K1B, STN, 0, stream>>>(sp);
    k_cmp<<<(K + CROWS - 1) / CROWS, CTN, 0, stream>>>(cp);
}

// Round 4
// 102.904 us; speedup vs baseline: 1.0380x; 1.0380x over previous
//
#include <hip/hip_runtime.h>
#include <math.h>

#define TOPK 2048
#define NCLS 80      // reference: randint(0, 80)
#define NBIN 4096    // score-digest bins (uniform scores -> ~5/bin)
#define CMAX 2560    // candidate key capacity (K + tie-bin slack)
#define TN   1024    // threads (16 waves)
#define CROWS 8      // output rows per block -> 256 blocks (1 per CU)

// ONE fused kernel. Key insight: the redundant-selection design means every
// block derives the COMPLETE top-K set in its own LDS -- so the compare
// phase can run in the same block with no inter-block communication, no
// workspace arrays, no second launch, no launch gap, no L2 round-trip.
struct P {
    const float* scores; const float* boxes; const int* classes;
    const float* sw1; const float* sb1; const float* sw2; const float* sb2;
    const float* sw3; const float* sb3;
    const float* lw1; const float* lb1; const float* lw2; const float* lb2;
    int M; int K;
    float* out_boxes; float* out_scores; float* out_cls;
};

__device__ __forceinline__ float iou_of(float xi, float yi, float ai,
                                        float x2i, float y2i, float4 bj) {
    float ix1 = fmaxf(xi, bj.x), iy1 = fmaxf(yi, bj.y);
    float ix2 = fminf(x2i, bj.x + bj.z), iy2 = fminf(y2i, bj.y + bj.w);
    float iw = fmaxf(ix2 - ix1, 0.0f), ih = fmaxf(iy2 - iy1, 0.0f);
    float inter = iw * ih;
    float uni = ai + bj.z * bj.w - inter;
    return inter / (uni + 1e-6f);
}

// monotone non-decreasing digest; single quantization used in all passes
__device__ __forceinline__ int digest12(float s) {
    int v = (int)(s * 4096.0f);
    return v < 0 ? 0 : (v > NBIN - 1 ? NBIN - 1 : v);
}

__device__ __forceinline__ float key_score(unsigned long long kk) {
    unsigned mono = (unsigned)(kk >> 32);
    unsigned ob = (mono & 0x80000000u) ? (mono & 0x7FFFFFFFu) : ~mono;
    return __uint_as_float(ob);
}

__global__ __launch_bounds__(TN, 1) void k_dacs(P p) {
    // ---- selection state (verified binned counting-rank, rounds 0-3) ----
    __shared__ int   bincur[NBIN];                // 16 KB count -> cursor
    __shared__ int   binbase[NBIN];               // 16 KB rank base
    __shared__ unsigned long long skeys[CMAX];    // 20 KB candidate keys
    __shared__ int   sfx[TN];                     // 4 KB inclusive suffix sums
    __shared__ int   wsum[TN / 64];               // wave-total suffix sums
    __shared__ int   sh_cT;
    // ---- full selected set, per block (no workspace round-trip) ----
    __shared__ float4 sbox[TOPK];                 // 32 KB
    __shared__ float  sscore[TOPK];               // 8 KB
    __shared__ short  scls[TOPK];                 // 4 KB
    __shared__ short  clist[TOPK];                // 4 KB rows grouped by class
    __shared__ int    ccnt[NCLS], ccur[NCLS], cstart[NCLS + 1];
    __shared__ int    wtot;
    // ---- compare-phase state ----
    __shared__ float  swt[914];                   // sup MLP 801 + lambda 113
    __shared__ float  wpart[TN / 64];             // per-wave D partials
    __shared__ int    rowc[CROWS];
    __shared__ int    prefix[CROWS + 1];
    __shared__ float  Ssum[CROWS], Drow[CROWS];

    int tid = threadIdx.x, bid = blockIdx.x;
    int M = p.M, K = p.K, M4 = M >> 2;
    int r0 = bid * CROWS;
    int nrows = K - r0; if (nrows > CROWS) nrows = CROWS;
    if (nrows <= 0) return;                       // block-uniform, pre-barrier

    // ---- stage MLP weights early (independent loads overlap selection) ----
    for (int t = tid; t < 224; t += TN) swt[t] = p.sw1[t];
    if (tid < 32) swt[224 + tid] = p.sb1[tid];
    for (int t = tid; t < 512; t += TN) swt[256 + t] = p.sw2[t];
    if (tid < 16) swt[768 + tid] = p.sb2[tid];
    if (tid < 16) swt[784 + tid] = p.sw3[tid];
    if (tid == 0) swt[800] = p.sb3[0];
    if (tid < 80) swt[801 + tid] = p.lw1[tid];
    if (tid < 16) swt[881 + tid] = p.lb1[tid];
    if (tid < 16) swt[897 + tid] = p.lw2[tid];
    if (tid == 0) swt[913] = p.lb2[0];

    for (int b = tid; b < NBIN; b += TN) bincur[b] = 0;
    if (tid < NCLS) ccnt[tid] = 0;
    if (tid < CROWS) Ssum[tid] = 0.0f;
    __syncthreads();

    // ---- sweep 1: histogram straight from global (vectorized) ----
    const float4* s4p = (const float4*)p.scores;
    for (int i4 = tid; i4 < M4; i4 += TN) {
        float4 v = s4p[i4];
        atomicAdd(&bincur[digest12(v.x)], 1);
        atomicAdd(&bincur[digest12(v.y)], 1);
        atomicAdd(&bincur[digest12(v.z)], 1);
        atomicAdd(&bincur[digest12(v.w)], 1);
    }
    for (int i = M4 * 4 + tid; i < M; i += TN)
        atomicAdd(&bincur[digest12(p.scores[i])], 1);
    __syncthreads();

    // ---- suffix scan (shuffle-based): sfx[t] = sum of chunk sums t.. ----
    {
        const int BPT = NBIN / TN;                // 4 bins per thread
        int c0 = tid * BPT, sum = 0;
        #pragma unroll
        for (int u = 0; u < BPT; u++) sum += bincur[c0 + u];
        int lane = tid & 63;
        int x = sum;
        #pragma unroll
        for (int off = 1; off < 64; off <<= 1) {  // in-wave inclusive suffix
            int v = __shfl_down(x, off, 64);
            if (lane + off < 64) x += v;
        }
        if (lane == 0) wsum[tid >> 6] = x;        // wave totals (16)
        __syncthreads();
        if (tid < TN / 64) {                      // suffix over wave totals
            int t = wsum[tid];
            #pragma unroll
            for (int off = 1; off < TN / 64; off <<= 1) {
                int v = __shfl_down(t, off, 64);
                if (tid + off < TN / 64) t += v;
            }
            wsum[tid] = t;
        }
        __syncthreads();
        int wid = tid >> 6;
        int higher = (wid < TN / 64 - 1) ? wsum[wid + 1] : 0;
        sfx[tid] = x + higher;                    // global inclusive suffix
    }
    __syncthreads();

    // ---- binbase per bin + find crossing bin cT ----
    {
        const int BPT = NBIN / TN;
        int running = (tid < TN - 1) ? sfx[tid + 1] : 0;
        int c0 = tid * BPT;
        for (int u = BPT - 1; u >= 0; u--) {
            int b = c0 + u, cnt = bincur[b];
            binbase[b] = running;
            if (running < K && running + cnt >= K) sh_cT = b;  // unique bin
            running += cnt;
        }
    }
    __syncthreads();
    int cT = sh_cT;
    for (int b = tid; b < NBIN; b += TN) bincur[b] = binbase[b];
    __syncthreads();

    // ---- sweep 2 (from L2, vectorized): scatter candidate keys ----
    // key = monotonic(score bits) << 32 | (0xFFFFFFFF - i): descending key ==
    // descending score, ties -> lower index (stable top_k semantics).
    for (int i4 = tid; i4 < M4; i4 += TN) {
        float4 v = s4p[i4];
        #pragma unroll
        for (int u = 0; u < 4; u++) {
            float s = (u == 0) ? v.x : (u == 1) ? v.y : (u == 2) ? v.z : v.w;
            int d = digest12(s);
            if (d >= cT) {
                int i = i4 * 4 + u;
                int slot = atomicAdd(&bincur[d], 1);
                if (slot < CMAX) {
                    unsigned b = __float_as_uint(s);
                    b = (b & 0x80000000u) ? ~b : (b | 0x80000000u);
                    skeys[slot] = ((unsigned long long)b << 32) |
                                  (unsigned long long)(0xFFFFFFFFu - (unsigned)i);
                }
            }
        }
    }
    for (int i = M4 * 4 + tid; i < M; i += TN) {
        float s = p.scores[i];
        int d = digest12(s);
        if (d >= cT) {
            int slot = atomicAdd(&bincur[d], 1);
            if (slot < CMAX) {
                unsigned b = __float_as_uint(s);
                b = (b & 0x80000000u) ? ~b : (b | 0x80000000u);
                skeys[slot] = ((unsigned long long)b << 32) |
                              (unsigned long long)(0xFFFFFFFFu - (unsigned)i);
            }
        }
    }
    __syncthreads();

    // ---- exact rank within bin (~5 peers) + gather FULL set into LDS ----
    int C = bincur[cT]; if (C > CMAX) C = CMAX;
    {
        const float4* boxes4 = (const float4*)p.boxes;
        for (int s = tid; s < C; s += TN) {
            unsigned long long ks = skeys[s];
            unsigned idx = 0xFFFFFFFFu - (unsigned)(ks & 0xFFFFFFFFull);
            float sc = key_score(ks);
            int d = digest12(sc);
            int st = binbase[d], en = bincur[d]; if (en > CMAX) en = CMAX;
            int r = binbase[d];
            for (int t = st; t < en; t++) r += (skeys[t] > ks) ? 1 : 0;
            if (r < K) {
                sbox[r] = boxes4[idx];
                sscore[r] = sc;
                scls[r] = (short)p.classes[idx];
            }
        }
    }
    __syncthreads();

    // ---- per-class lists in LDS (verified 2-wave shuffle scan) ----
    for (int r = tid; r < K; r += TN) atomicAdd(&ccnt[scls[r]], 1);
    __syncthreads();
    {
        int x = 0, v = 0;
        if (tid < 128) {
            v = (tid < NCLS) ? ccnt[tid] : 0;
            x = v;
            #pragma unroll
            for (int off = 1; off < 64; off <<= 1) {
                int t = __shfl_up(x, off, 64);
                if ((tid & 63) >= off) x += t;
            }
            if (tid == 63) wtot = x;              // total of classes 0..63
        }
        __syncthreads();
        if (tid < NCLS) {
            int excl = x - v + ((tid >= 64) ? wtot : 0);
            ccur[tid] = excl;
            cstart[tid] = excl;
        }
        if (tid == 0) cstart[NCLS] = K;
        __syncthreads();
        for (int r = tid; r < K; r += TN) {
            int pos = atomicAdd(&ccur[scls[r]], 1);
            clist[pos] = (short)r;
        }
    }
    __syncthreads();

    // ---- Phase A: D row means; 2 waves per row, boxes from LDS ----
    {
        int wv = tid >> 6, lane = tid & 63;
        int row = wv >> 1, half = wv & 1;
        float dsum = 0.0f;
        if (row < nrows) {
            float4 bi = sbox[r0 + row];
            float ai = bi.z * bi.w, x2i = bi.x + bi.z, y2i = bi.y + bi.w;
            for (int j = lane + (half << 6); j < K; j += 128)
                dsum += iou_of(bi.x, bi.y, ai, x2i, y2i, sbox[j]);
            #pragma unroll
            for (int off = 32; off >= 1; off >>= 1)
                dsum += __shfl_xor(dsum, off, 64);
        }
        if (lane == 0) wpart[wv] = dsum;
    }

    // ---- per-row pair ranges ----
    if (tid < CROWS) {
        int st = 0, cnt = 0;
        if (tid < nrows) {
            int c = scls[r0 + tid];
            st = cstart[c];
            cnt = cstart[c + 1] - st;
        }
        rowc[tid] = st;
        prefix[tid] = cnt;                        // temp: counts
    }
    __syncthreads();
    if (tid < nrows) Drow[tid] = (wpart[2 * tid] + wpart[2 * tid + 1]) / (float)K;
    if (tid == 0) {                               // CROWS-element exclusive prefix
        int acc = 0;
        #pragma unroll
        for (int rr = 0; rr < CROWS; rr++) { int t = prefix[rr]; prefix[rr] = acc; acc += t; }
        prefix[CROWS] = acc;
    }
    __syncthreads();

    int Pb = prefix[CROWS];
    const float* W1 = swt;       const float* B1 = swt + 224;
    const float* W2 = swt + 256; const float* B2 = swt + 768;
    const float* W3 = swt + 784; float B3 = swt[800];

    // ---- Phase B: flat per-pair fused MLP (same-class pairs only) ----
    for (int pp = tid; pp < Pb; pp += TN) {
        int lo = 0, hi = CROWS;
        while (hi - lo > 1) {
            int mid = (lo + hi) >> 1;
            if (prefix[mid] <= pp) lo = mid; else hi = mid;
        }
        int row = lo;
        int j = (int)clist[rowc[row] + (pp - prefix[row])];
        float4 bi = sbox[r0 + row];
        float4 bj = sbox[j];
        float ai = bi.z * bi.w, x2i = bi.x + bi.z, y2i = bi.y + bi.w;
        float iou = iou_of(bi.x, bi.y, ai, x2i, y2i, bj);
        float f1 = fabsf(bi.x - bj.x), f2 = fabsf(bi.y - bj.y);
        float f3 = fabsf(bi.z - bj.z), f4 = fabsf(bi.w - bj.w);
        float f5 = sscore[r0 + row], f6 = sscore[j];
        float acc2[16];
        #pragma unroll
        for (int q = 0; q < 16; q++) acc2[q] = B2[q];
        #pragma unroll 2
        for (int o = 0; o < 32; o++) {
            float a = B1[o];
            a += iou * W1[0 * 32 + o];
            a += f1 * W1[1 * 32 + o];
            a += f2 * W1[2 * 32 + o];
            a += f3 * W1[3 * 32 + o];
            a += f4 * W1[4 * 32 + o];
            a += f5 * W1[5 * 32 + o];
            a += f6 * W1[6 * 32 + o];
            float h = fmaxf(a, 0.0f);
            #pragma unroll
            for (int q = 0; q < 16; q++) acc2[q] += h * W2[o * 16 + q];
        }
        float acc3 = B3;
        #pragma unroll
        for (int q = 0; q < 16; q++) acc3 += fmaxf(acc2[q], 0.0f) * W3[q];
        atomicAdd(&Ssum[row], iou / (1.0f + expf(-acc3)));
    }
    __syncthreads();

    // ---- finale: lambda MLP + outputs for this block's rows ----
    if (tid < nrows) {
        int r = r0 + tid;
        float4 bi = sbox[r];
        float si = sscore[r];
        const float* LW1 = swt + 801; const float* LB1 = swt + 881;
        const float* LW2 = swt + 897; float LB2 = swt[913];
        float in5[5] = { bi.x, bi.y, bi.z, bi.w, si };
        float acc = LB2;
        #pragma unroll
        for (int o = 0; o < 16; o++) {
            float a2 = LB1[o];
            #pragma unroll
            for (int f = 0; f < 5; f++) a2 += in5[f] * LW1[f * 16 + o];
            acc += fmaxf(a2, 0.0f) * LW2[o];
        }
        float lam = 1.0f / (1.0f + expf(-acc));
        ((float4*)p.out_boxes)[r] = bi;
        p.out_cls[r] = (float)scls[r];
        p.out_scores[r] = si * expf(-lam * Ssum[tid] * Drow[tid]);
    }
}

extern "C" void kernel_launch(void* const* d_in, const int* in_sizes, int n_in,
                              void* d_out, int out_size, void* d_ws, size_t ws_size,
                              hipStream_t stream) {
    int M = in_sizes[1];
    int K = (M < TOPK) ? M : TOPK;

    P dp;
    dp.scores  = (const float*)d_in[1];
    dp.boxes   = (const float*)d_in[0];
    dp.classes = (const int*)d_in[2];
    dp.sw1 = (const float*)d_in[3];  dp.sb1 = (const float*)d_in[4];
    dp.sw2 = (const float*)d_in[5];  dp.sb2 = (const float*)d_in[6];
    dp.sw3 = (const float*)d_in[7];  dp.sb3 = (const float*)d_in[8];
    dp.lw1 = (const float*)d_in[9];  dp.lb1 = (const float*)d_in[10];
    dp.lw2 = (const float*)d_in[11]; dp.lb2 = (const float*)d_in[12];
    dp.M = M; dp.K = K;
    dp.out_boxes  = (float*)d_out;
    dp.out_scores = (float*)d_out + (size_t)K * 4;
    dp.out_cls    = (float*)d_out + (size_t)K * 5;

    int nb = (K + CROWS - 1) / CROWS;
    k_dacs<<<nb, TN, 0, stream>>>(dp);
}